// Round 3
// baseline (947.079 us; speedup 1.0000x reference)
//
#include <hip/hip_runtime.h>
#include <hip/hip_bf16.h>

typedef short short8 __attribute__((ext_vector_type(8)));
typedef float floatx4 __attribute__((ext_vector_type(4)));

#define BB 256
#define OO 1024
#define HH 2048
#define SS 12

__device__ __forceinline__ __hip_bfloat16 f2b(float x) { return __float2bfloat16(x); }
__device__ __forceinline__ float sigf(float x) { return 1.0f / (1.0f + expf(-x)); }

// Convert 8 consecutive fp32 at src -> 8 bf16 stored as one short8
__device__ __forceinline__ short8 cvt8(const float* __restrict__ src) {
    float4 lo = *(const float4*)src;
    float4 hi = *(const float4*)(src + 4);
    union { short8 s; __hip_bfloat16 h[8]; } u;
    u.h[0] = f2b(lo.x); u.h[1] = f2b(lo.y); u.h[2] = f2b(lo.z); u.h[3] = f2b(lo.w);
    u.h[4] = f2b(hi.x); u.h[5] = f2b(hi.y); u.h[6] = f2b(hi.z); u.h[7] = f2b(hi.w);
    return u.s;
}

// ---------------------------------------------------------------------------
// Attention (all fp32): logits[s] = dot(concat(x0,h00), attn_W[s]) + b[s];
// softmax over S=12; attn_out[b,h] = sum_s w[s]*enc[s,b,h]
// ---------------------------------------------------------------------------
__global__ __launch_bounds__(256)
void attn_kernel(const float* __restrict__ x0,
                 const float* __restrict__ h00,
                 const float* __restrict__ enc,
                 const float* __restrict__ attn_W,
                 const float* __restrict__ attn_b,
                 float* __restrict__ attn_out)
{
    const int b = blockIdx.x;
    const int tid = threadIdx.x;
    const int lane = tid & 63;
    const int wave = tid >> 6;

    float part[SS];
#pragma unroll
    for (int s = 0; s < SS; s++) part[s] = 0.f;

    for (int e = tid; e < OO + HH; e += 256) {
        float val = (e < OO) ? x0[b * OO + e] : h00[b * HH + (e - OO)];
#pragma unroll
        for (int s = 0; s < SS; s++)
            part[s] += val * attn_W[s * (OO + HH) + e];
    }
#pragma unroll
    for (int s = 0; s < SS; s++) {
#pragma unroll
        for (int off = 32; off > 0; off >>= 1)
            part[s] += __shfl_down(part[s], off);
    }
    __shared__ float red[4][SS];
    __shared__ float wbuf[SS];
    if (lane == 0) {
#pragma unroll
        for (int s = 0; s < SS; s++) red[wave][s] = part[s];
    }
    __syncthreads();
    if (tid == 0) {
        float logits[SS];
        float mx = -1e30f;
        for (int s = 0; s < SS; s++) {
            logits[s] = red[0][s] + red[1][s] + red[2][s] + red[3][s] + attn_b[s];
            mx = fmaxf(mx, logits[s]);
        }
        float sum = 0.f;
        for (int s = 0; s < SS; s++) { logits[s] = expf(logits[s] - mx); sum += logits[s]; }
        float inv = 1.0f / sum;
        for (int s = 0; s < SS; s++) wbuf[s] = logits[s] * inv;
    }
    __syncthreads();

    for (int h = tid; h < HH; h += 256) {
        float acc = 0.f;
#pragma unroll
        for (int s = 0; s < SS; s++)
            acc += wbuf[s] * enc[((size_t)s * BB + b) * HH + h];
        attn_out[(size_t)b * HH + h] = acc;
    }
}

// ---------------------------------------------------------------------------
// Dual-segment GEMM: C[256,N] = act(A1@W1^T + A2@W2^T + b1 + b2), fp32 I/O,
// bf16 MFMA compute (fp32->bf16 RTNE at LDS staging).
// Tile BM=64, BN=128, BK=32; 4 waves (2x2), wave tile 32x64.
// ---------------------------------------------------------------------------
template<bool RELU>
__global__ __launch_bounds__(256)
void gemm_dual(const float* __restrict__ A1, int lda1,
               const float* __restrict__ W1, int ldw1, int K1,
               const float* __restrict__ A2, int lda2,
               const float* __restrict__ W2, int ldw2, int K2,
               const float* __restrict__ bias1,
               const float* __restrict__ bias2,
               float* __restrict__ Cout, int ldc)
{
    __shared__ __attribute__((aligned(16))) __hip_bfloat16 As[64][40];
    __shared__ __attribute__((aligned(16))) __hip_bfloat16 Ws[128][40];
    const int tid = threadIdx.x;
    const int lane = tid & 63;
    const int wave = tid >> 6;
    const int wm = wave >> 1, wn = wave & 1;
    const int quad = lane >> 4, l15 = lane & 15;
    const int m_base = blockIdx.y * 64;
    const int n_base = blockIdx.x * 128;
    const int srow = tid >> 2;
    const int scol = (tid & 3) << 3;

    floatx4 acc[2][4];
#pragma unroll
    for (int mi = 0; mi < 2; mi++)
#pragma unroll
        for (int ni = 0; ni < 4; ni++)
            acc[mi][ni] = (floatx4){0.f, 0.f, 0.f, 0.f};

    const float* Aseg[2] = {A1, A2};
    const float* Wseg[2] = {W1, W2};
    const int ldas[2] = {lda1, lda2};
    const int ldws[2] = {ldw1, ldw2};
    const int Ks[2] = {K1, K2};

    for (int seg = 0; seg < 2; seg++) {
        const float* __restrict__ A = Aseg[seg];
        const float* __restrict__ W = Wseg[seg];
        const int lda = ldas[seg], ldw = ldws[seg], K = Ks[seg];
        for (int k0 = 0; k0 < K; k0 += 32) {
            __syncthreads();
            *(short8*)(&As[srow][scol]) =
                cvt8(A + (size_t)(m_base + srow) * lda + k0 + scol);
            *(short8*)(&Ws[srow][scol]) =
                cvt8(W + (size_t)(n_base + srow) * ldw + k0 + scol);
            *(short8*)(&Ws[srow + 64][scol]) =
                cvt8(W + (size_t)(n_base + srow + 64) * ldw + k0 + scol);
            __syncthreads();

            short8 af[2], bfr[4];
#pragma unroll
            for (int mi = 0; mi < 2; mi++)
                af[mi] = *(const short8*)(&As[wm * 32 + mi * 16 + l15][quad * 8]);
#pragma unroll
            for (int ni = 0; ni < 4; ni++)
                bfr[ni] = *(const short8*)(&Ws[wn * 64 + ni * 16 + l15][quad * 8]);
#pragma unroll
            for (int mi = 0; mi < 2; mi++)
#pragma unroll
                for (int ni = 0; ni < 4; ni++)
                    acc[mi][ni] = __builtin_amdgcn_mfma_f32_16x16x32_bf16(
                        af[mi], bfr[ni], acc[mi][ni], 0, 0, 0);
        }
    }

    // C/D layout: col=lane&15, row=quad*4+reg  [m89/m91 verified]
#pragma unroll
    for (int mi = 0; mi < 2; mi++) {
#pragma unroll
        for (int ni = 0; ni < 4; ni++) {
            const int col = n_base + wn * 64 + ni * 16 + l15;
            float bsum = bias1[col] + (bias2 ? bias2[col] : 0.f);
#pragma unroll
            for (int r = 0; r < 4; r++) {
                const int row = m_base + wm * 32 + mi * 16 + quad * 4 + r;
                float v = acc[mi][ni][r] + bsum;
                if (RELU) v = fmaxf(v, 0.f);
                Cout[(size_t)row * ldc + col] = v;
            }
        }
    }
}

// ---------------------------------------------------------------------------
// Fused LSTM layer: gates = A1@Wih^T + A2@Whh^T + bih + bhh (W rows i|f|g|o,
// 2048 each); LSTM cell fused in epilogue -> h,c fp32.
// Block: 64 batch rows x 32 h-cols, all 4 gates. grid = (64, 4).
// ---------------------------------------------------------------------------
__global__ __launch_bounds__(256)
void lstm_fused(const float* __restrict__ A1, int lda1,
                const float* __restrict__ Wih, int K1,
                const float* __restrict__ A2,   // h_prev [256,2048]
                const float* __restrict__ Whh,  // [8192,2048]
                const float* __restrict__ bih,
                const float* __restrict__ bhh,
                const float* __restrict__ c0,
                float* __restrict__ h_out,
                float* __restrict__ c_out)
{
    __shared__ __attribute__((aligned(16))) __hip_bfloat16 As[64][40];
    __shared__ __attribute__((aligned(16))) __hip_bfloat16 Ws[128][40];  // 4 gates x 32 rows
    const int tid = threadIdx.x;
    const int lane = tid & 63;
    const int wave = tid >> 6;
    const int wm = wave >> 1, wn = wave & 1;
    const int quad = lane >> 4, l15 = lane & 15;
    const int m_base = blockIdx.y * 64;
    const int n_base = blockIdx.x * 32;   // h-column base
    const int srow = tid >> 2;
    const int scol = (tid & 3) << 3;

    // Ws row r (0..127): gate = r>>5 -> W row gate*2048 + n_base + (r&31)
    const int wr0 = ((srow >> 5) * HH) + n_base + (srow & 31);
    const int wr1 = (((srow + 64) >> 5) * HH) + n_base + ((srow + 64) & 31);

    floatx4 acc[4][2];   // [gate][mi]
#pragma unroll
    for (int g = 0; g < 4; g++)
#pragma unroll
        for (int mi = 0; mi < 2; mi++)
            acc[g][mi] = (floatx4){0.f, 0.f, 0.f, 0.f};

    const float* Aseg[2] = {A1, A2};
    const float* Wseg[2] = {Wih, Whh};
    const int ldas[2] = {lda1, HH};
    const int Ks[2] = {K1, HH};

    for (int seg = 0; seg < 2; seg++) {
        const float* __restrict__ A = Aseg[seg];
        const float* __restrict__ W = Wseg[seg];
        const int lda = ldas[seg], K = Ks[seg];
        for (int k0 = 0; k0 < K; k0 += 32) {
            __syncthreads();
            *(short8*)(&As[srow][scol]) =
                cvt8(A + (size_t)(m_base + srow) * lda + k0 + scol);
            *(short8*)(&Ws[srow][scol]) =
                cvt8(W + (size_t)wr0 * K + k0 + scol);
            *(short8*)(&Ws[srow + 64][scol]) =
                cvt8(W + (size_t)wr1 * K + k0 + scol);
            __syncthreads();

            short8 af[2], bfr[4];
#pragma unroll
            for (int mi = 0; mi < 2; mi++)
                af[mi] = *(const short8*)(&As[wm * 32 + mi * 16 + l15][quad * 8]);
#pragma unroll
            for (int g = 0; g < 4; g++)
                bfr[g] = *(const short8*)(&Ws[g * 32 + wn * 16 + l15][quad * 8]);
#pragma unroll
            for (int g = 0; g < 4; g++)
#pragma unroll
                for (int mi = 0; mi < 2; mi++)
                    acc[g][mi] = __builtin_amdgcn_mfma_f32_16x16x32_bf16(
                        af[mi], bfr[g], acc[g][mi], 0, 0, 0);
        }
    }

    // epilogue: lane holds i,f,g,o for (row,col); fused LSTM cell, fp32 out.
    const int col = n_base + wn * 16 + l15;
    float bsum[4];
#pragma unroll
    for (int g = 0; g < 4; g++)
        bsum[g] = bih[g * HH + col] + bhh[g * HH + col];

#pragma unroll
    for (int mi = 0; mi < 2; mi++) {
#pragma unroll
        for (int r = 0; r < 4; r++) {
            const int row = m_base + wm * 32 + mi * 16 + quad * 4 + r;
            const size_t idx = (size_t)row * HH + col;
            float gi = acc[0][mi][r] + bsum[0];
            float gf = acc[1][mi][r] + bsum[1];
            float gg = acc[2][mi][r] + bsum[2];
            float go = acc[3][mi][r] + bsum[3];
            float c0v = c0[idx];
            float cn = sigf(gf) * c0v + sigf(gi) * tanhf(gg);
            float hn = sigf(go) * tanhf(cn);
            h_out[idx] = hn;
            c_out[idx] = cn;
        }
    }
}

// ---------------------------------------------------------------------------
extern "C" void kernel_launch(void* const* d_in, const int* in_sizes, int n_in,
                              void* d_out, int out_size, void* d_ws, size_t ws_size,
                              hipStream_t stream) {
    const float* x      = (const float*)d_in[0];   // [1,256,1024]
    const float* h0     = (const float*)d_in[1];   // [2,256,2048]
    const float* c0     = (const float*)d_in[2];   // [2,256,2048]
    const float* enc    = (const float*)d_in[3];   // [12,256,2048]
    const float* attn_W = (const float*)d_in[4];   // [12,3072]
    const float* attn_b = (const float*)d_in[5];   // [12]
    const float* comb_W = (const float*)d_in[6];   // [1024,3072]
    const float* comb_b = (const float*)d_in[7];   // [1024]
    const float* Wih0   = (const float*)d_in[8];   // [8192,1024]
    const float* Whh0   = (const float*)d_in[9];   // [8192,2048]
    const float* bih0   = (const float*)d_in[10];
    const float* bhh0   = (const float*)d_in[11];
    const float* Wih1   = (const float*)d_in[12];  // [8192,2048]
    const float* Whh1   = (const float*)d_in[13];  // [8192,2048]
    const float* bih1   = (const float*)d_in[14];
    const float* bhh1   = (const float*)d_in[15];
    const float* out_W  = (const float*)d_in[16];  // [1024,2048]
    const float* out_b  = (const float*)d_in[17];

    // d_out (fp32): prediction [256*1024], h_new [2*256*2048], c_new [2*256*2048]
    float* pred = (float*)d_out;
    float* h1   = pred + 262144;
    float* h2   = h1 + 524288;
    float* c1   = h2 + 524288;
    float* c2   = c1 + 524288;
    const float* h0_l0 = h0;
    const float* h0_l1 = h0 + 524288;
    const float* c0_l0 = c0;
    const float* c0_l1 = c0 + 524288;

    // Scratch aliased inside d_out (zero d_ws usage):
    //   xin      aliases pred (written step 2, read step 3; pred written step 5)
    //   attn_out aliases c2   (written step 1, read step 2; c2 written step 4)
    float* xin      = pred;
    float* attn_out = c2;

    // 1. attention
    attn_kernel<<<dim3(BB), dim3(256), 0, stream>>>(x, h0_l0, enc, attn_W, attn_b, attn_out);

    // 2. comb: xin = relu([x0|attn] @ comb_W^T + comb_b)   N=1024
    gemm_dual<true><<<dim3(OO / 128, 4), dim3(256), 0, stream>>>(
        x, OO, comb_W, OO + HH, OO,
        attn_out, HH, comb_W + OO, OO + HH, HH,
        comb_b, nullptr, xin, OO);

    // 3. LSTM layer 0 (fused gates+cell) -> h1, c1
    lstm_fused<<<dim3(HH / 32, 4), dim3(256), 0, stream>>>(
        xin, OO, Wih0, OO, h0_l0, Whh0, bih0, bhh0, c0_l0, h1, c1);

    // 4. LSTM layer 1 (fused) -> h2, c2 (c2 overwrites attn_out, already consumed)
    lstm_fused<<<dim3(HH / 32, 4), dim3(256), 0, stream>>>(
        h1, HH, Wih1, HH, h0_l1, Whh1, bih1, bhh1, c0_l1, h2, c2);

    // 5. prediction = h2 @ out_W^T + out_b   N=1024 (overwrites xin)
    gemm_dual<false><<<dim3(OO / 128, 4), dim3(256), 0, stream>>>(
        h2, HH, out_W, HH, HH,
        nullptr, 0, nullptr, 0, 0,
        out_b, nullptr, pred, OO);
}

// Round 4
// 554.935 us; speedup vs baseline: 1.7066x; 1.7066x over previous
//
#include <hip/hip_runtime.h>
#include <hip/hip_bf16.h>

typedef short short8 __attribute__((ext_vector_type(8)));
typedef short short4v __attribute__((ext_vector_type(4)));
typedef float floatx4 __attribute__((ext_vector_type(4)));

#define BB 256
#define OO 1024
#define HH 2048
#define SS 12

__device__ __forceinline__ __hip_bfloat16 f2b(float x) { return __float2bfloat16(x); }
__device__ __forceinline__ float sigf(float x) { return 1.0f / (1.0f + expf(-x)); }

__device__ __forceinline__ short8 cvt8v(float4 lo, float4 hi) {
    union { short8 s; __hip_bfloat16 h[8]; } u;
    u.h[0] = f2b(lo.x); u.h[1] = f2b(lo.y); u.h[2] = f2b(lo.z); u.h[3] = f2b(lo.w);
    u.h[4] = f2b(hi.x); u.h[5] = f2b(hi.y); u.h[6] = f2b(hi.z); u.h[7] = f2b(hi.w);
    return u.s;
}
__device__ __forceinline__ short4v cvt4v(float4 v) {
    union { short4v s; __hip_bfloat16 h[4]; } u;
    u.h[0] = f2b(v.x); u.h[1] = f2b(v.y); u.h[2] = f2b(v.z); u.h[3] = f2b(v.w);
    return u.s;
}
__device__ __forceinline__ unsigned cvt2v(float2 v) {
    union { unsigned s; __hip_bfloat16 h[2]; } u;
    u.h[0] = f2b(v.x); u.h[1] = f2b(v.y);
    return u.s;
}

// ---------------------------------------------------------------------------
// Attention (fp32): softmax(concat(x0,h00)@attn_W^T + b) over S=12,
// then attn_out = sum_s w[s]*enc[s]
// ---------------------------------------------------------------------------
__global__ __launch_bounds__(256)
void attn_kernel(const float* __restrict__ x0,
                 const float* __restrict__ h00,
                 const float* __restrict__ enc,
                 const float* __restrict__ attn_W,
                 const float* __restrict__ attn_b,
                 float* __restrict__ attn_out)
{
    const int b = blockIdx.x;
    const int tid = threadIdx.x;
    const int lane = tid & 63;
    const int wave = tid >> 6;

    float part[SS];
#pragma unroll
    for (int s = 0; s < SS; s++) part[s] = 0.f;

    for (int e = tid; e < OO + HH; e += 256) {
        float val = (e < OO) ? x0[b * OO + e] : h00[b * HH + (e - OO)];
#pragma unroll
        for (int s = 0; s < SS; s++)
            part[s] += val * attn_W[s * (OO + HH) + e];
    }
#pragma unroll
    for (int s = 0; s < SS; s++) {
#pragma unroll
        for (int off = 32; off > 0; off >>= 1)
            part[s] += __shfl_down(part[s], off);
    }
    __shared__ float red[4][SS];
    __shared__ float wbuf[SS];
    if (lane == 0) {
#pragma unroll
        for (int s = 0; s < SS; s++) red[wave][s] = part[s];
    }
    __syncthreads();
    if (tid == 0) {
        float logits[SS];
        float mx = -1e30f;
        for (int s = 0; s < SS; s++) {
            logits[s] = red[0][s] + red[1][s] + red[2][s] + red[3][s] + attn_b[s];
            mx = fmaxf(mx, logits[s]);
        }
        float sum = 0.f;
        for (int s = 0; s < SS; s++) { logits[s] = expf(logits[s] - mx); sum += logits[s]; }
        float inv = 1.0f / sum;
        for (int s = 0; s < SS; s++) wbuf[s] = logits[s] * inv;
    }
    __syncthreads();

    for (int h = tid; h < HH; h += 256) {
        float acc = 0.f;
#pragma unroll
        for (int s = 0; s < SS; s++)
            acc += wbuf[s] * enc[((size_t)s * BB + b) * HH + h];
        attn_out[(size_t)b * HH + h] = acc;
    }
}

// ---------------------------------------------------------------------------
// Dual-segment GEMM, pipelined: C[256,N] = act(A1@W1^T + A2@W2^T + b1 + b2)
// fp32 I/O, bf16 MFMA. BM=16, BN=64, BK=32. 256 thr = 4 waves, wave = 16 cols.
// grid (N/64, 256/16): same-n m-blocks land on same XCD (ids differ by N/64).
// Double-buffered LDS with register prefetch; one barrier per K-iter.
// ---------------------------------------------------------------------------
template<bool RELU>
__global__ __launch_bounds__(256)
void gemm_dual(const float* __restrict__ A1, int K1,
               const float* __restrict__ W1, int ldw1, int ofs1,
               const float* __restrict__ A2, int K2,
               const float* __restrict__ W2, int ldw2, int ofs2,
               const float* __restrict__ bias1,
               const float* __restrict__ bias2,
               float* __restrict__ Cout, int ldc)
{
    __shared__ __attribute__((aligned(16))) __hip_bfloat16 As[2][16][48];
    __shared__ __attribute__((aligned(16))) __hip_bfloat16 Ws[2][64][48];
    const int tid = threadIdx.x;
    const int lane = tid & 63;
    const int wave = tid >> 6;
    const int quad = lane >> 4, l15 = lane & 15;
    const int m_base = blockIdx.y * 16;
    const int n_base = blockIdx.x * 64;

    // staging: A 16x32 = 512 elems -> 2/thread; W 64x32 = 2048 -> 8/thread
    const int arow = tid >> 4, acol = (tid & 15) << 1;
    const int wrow = tid >> 2, wcol = (tid & 3) << 3;

    const int n1 = K1 >> 5;
    const int nT = n1 + (K2 >> 5);

    const float* baseA1 = A1 + (size_t)(m_base + arow) * K1 + acol;
    const float* baseA2 = A2 + (size_t)(m_base + arow) * K2 + acol;
    const float* baseW1 = W1 + (size_t)(n_base + wrow) * ldw1 + ofs1 + wcol;
    const float* baseW2 = W2 + (size_t)(n_base + wrow) * ldw2 + ofs2 + wcol;

    float2 pa;
    float4 pw0, pw1;
    pa  = *(const float2*)(baseA1);
    pw0 = *(const float4*)(baseW1);
    pw1 = *(const float4*)(baseW1 + 4);

    floatx4 acc = (floatx4){0.f, 0.f, 0.f, 0.f};

    for (int t = 0; t < nT; t++) {
        const int buf = t & 1;
        *(unsigned*)(&As[buf][arow][acol]) = cvt2v(pa);
        *(short8*)(&Ws[buf][wrow][wcol])   = cvt8v(pw0, pw1);
        __syncthreads();
        const int t1 = t + 1;
        if (t1 < nT) {
            const float *ap, *wp;
            if (t1 < n1) { ap = baseA1 + (t1 << 5);        wp = baseW1 + (t1 << 5); }
            else         { ap = baseA2 + ((t1 - n1) << 5); wp = baseW2 + ((t1 - n1) << 5); }
            pa  = *(const float2*)(ap);
            pw0 = *(const float4*)(wp);
            pw1 = *(const float4*)(wp + 4);
        }
        short8 af = *(const short8*)(&As[buf][l15][quad * 8]);
        short8 bf = *(const short8*)(&Ws[buf][wave * 16 + l15][quad * 8]);
        acc = __builtin_amdgcn_mfma_f32_16x16x32_bf16(af, bf, acc, 0, 0, 0);
    }

    // C/D: col=lane&15, row=quad*4+r
    const int col = n_base + wave * 16 + l15;
    float bsum = bias1[col] + (bias2 ? bias2[col] : 0.f);
#pragma unroll
    for (int r = 0; r < 4; r++) {
        const int row = m_base + quad * 4 + r;
        float v = acc[r] + bsum;
        if (RELU) v = fmaxf(v, 0.f);
        Cout[(size_t)row * ldc + col] = v;
    }
}

// ---------------------------------------------------------------------------
// Fused LSTM layer, pipelined: gates = A1@Wih^T + A2@Whh^T + bih + bhh
// (W rows i|f|g|o, 2048 each), LSTM cell in epilogue -> h,c fp32.
// 512 thr = 8 waves. BM=128 (wave = 16 rows), 16 h-cols x 4 gates = 64 W rows.
// grid (2048/16=128, 256/128=2): m-pair ids differ by 128 -> same XCD.
// ---------------------------------------------------------------------------
__global__ __launch_bounds__(512)
void lstm_fused(const float* __restrict__ A1, int K1,
                const float* __restrict__ Wih,
                const float* __restrict__ A2,   // h_prev [256,2048]
                const float* __restrict__ Whh,  // [8192,2048]
                const float* __restrict__ bih,
                const float* __restrict__ bhh,
                const float* __restrict__ c0,
                float* __restrict__ h_out,
                float* __restrict__ c_out)
{
    __shared__ __attribute__((aligned(16))) __hip_bfloat16 As[2][128][48];
    __shared__ __attribute__((aligned(16))) __hip_bfloat16 Ws[2][64][48];
    const int tid = threadIdx.x;
    const int lane = tid & 63;
    const int wave = tid >> 6;           // 0..7 -> m-subtile
    const int quad = lane >> 4, l15 = lane & 15;
    const int m_base = blockIdx.y * 128;
    const int n_base = blockIdx.x * 16;  // h-col base

    // staging: A 128x32 = 4096 -> 8/thread; W 64x32 = 2048 -> 4/thread
    const int arow = tid >> 2, acol = (tid & 3) << 3;
    const int wrow = tid >> 3, wcol = (tid & 7) << 2;
    // W row: gate = wrow>>4, hcol = wrow&15
    const int grow = (wrow >> 4) * HH + n_base + (wrow & 15);

    const int n1 = K1 >> 5;
    const int nT = n1 + (HH >> 5);

    const float* baseA1 = A1 + (size_t)(m_base + arow) * K1 + acol;
    const float* baseA2 = A2 + (size_t)(m_base + arow) * HH + acol;
    const float* baseW1 = Wih + (size_t)grow * K1 + wcol;
    const float* baseW2 = Whh + (size_t)grow * HH + wcol;

    float4 pa0, pa1, pw;
    pa0 = *(const float4*)(baseA1);
    pa1 = *(const float4*)(baseA1 + 4);
    pw  = *(const float4*)(baseW1);

    floatx4 acc[4];
#pragma unroll
    for (int g = 0; g < 4; g++) acc[g] = (floatx4){0.f, 0.f, 0.f, 0.f};

    for (int t = 0; t < nT; t++) {
        const int buf = t & 1;
        *(short8*)(&As[buf][arow][acol])  = cvt8v(pa0, pa1);
        *(short4v*)(&Ws[buf][wrow][wcol]) = cvt4v(pw);
        __syncthreads();
        const int t1 = t + 1;
        if (t1 < nT) {
            const float *ap, *wp;
            if (t1 < n1) { ap = baseA1 + (t1 << 5);        wp = baseW1 + (t1 << 5); }
            else         { ap = baseA2 + ((t1 - n1) << 5); wp = baseW2 + ((t1 - n1) << 5); }
            pa0 = *(const float4*)(ap);
            pa1 = *(const float4*)(ap + 4);
            pw  = *(const float4*)(wp);
        }
        short8 af = *(const short8*)(&As[buf][wave * 16 + l15][quad * 8]);
#pragma unroll
        for (int g = 0; g < 4; g++) {
            short8 bf = *(const short8*)(&Ws[buf][g * 16 + l15][quad * 8]);
            acc[g] = __builtin_amdgcn_mfma_f32_16x16x32_bf16(af, bf, acc[g], 0, 0, 0);
        }
    }

    // epilogue: lane holds i,f,g,o for (row,col); fused LSTM cell, fp32 out.
    const int col = n_base + l15;
    float bsum[4];
#pragma unroll
    for (int g = 0; g < 4; g++)
        bsum[g] = bih[g * HH + col] + bhh[g * HH + col];

#pragma unroll
    for (int r = 0; r < 4; r++) {
        const int row = m_base + wave * 16 + quad * 4 + r;
        const size_t idx = (size_t)row * HH + col;
        float gi = acc[0][r] + bsum[0];
        float gf = acc[1][r] + bsum[1];
        float gg = acc[2][r] + bsum[2];
        float go = acc[3][r] + bsum[3];
        float c0v = c0[idx];
        float cn = sigf(gf) * c0v + sigf(gi) * tanhf(gg);
        float hn = sigf(go) * tanhf(cn);
        h_out[idx] = hn;
        c_out[idx] = cn;
    }
}

// ---------------------------------------------------------------------------
extern "C" void kernel_launch(void* const* d_in, const int* in_sizes, int n_in,
                              void* d_out, int out_size, void* d_ws, size_t ws_size,
                              hipStream_t stream) {
    const float* x      = (const float*)d_in[0];
    const float* h0     = (const float*)d_in[1];
    const float* c0     = (const float*)d_in[2];
    const float* enc    = (const float*)d_in[3];
    const float* attn_W = (const float*)d_in[4];
    const float* attn_b = (const float*)d_in[5];
    const float* comb_W = (const float*)d_in[6];
    const float* comb_b = (const float*)d_in[7];
    const float* Wih0   = (const float*)d_in[8];
    const float* Whh0   = (const float*)d_in[9];
    const float* bih0   = (const float*)d_in[10];
    const float* bhh0   = (const float*)d_in[11];
    const float* Wih1   = (const float*)d_in[12];
    const float* Whh1   = (const float*)d_in[13];
    const float* bih1   = (const float*)d_in[14];
    const float* bhh1   = (const float*)d_in[15];
    const float* out_W  = (const float*)d_in[16];
    const float* out_b  = (const float*)d_in[17];

    float* pred = (float*)d_out;
    float* h1   = pred + 262144;
    float* h2   = h1 + 524288;
    float* c1   = h2 + 524288;
    float* c2   = c1 + 524288;
    const float* h0_l0 = h0;
    const float* h0_l1 = h0 + 524288;
    const float* c0_l0 = c0;
    const float* c0_l1 = c0 + 524288;

    // Scratch aliased inside d_out (zero d_ws usage):
    //   xin aliases pred (read step 3; pred written step 5)
    //   attn_out aliases c2 (read step 2; c2 written step 4)
    float* xin      = pred;
    float* attn_out = c2;

    // 1. attention
    attn_kernel<<<dim3(BB), dim3(256), 0, stream>>>(x, h0_l0, enc, attn_W, attn_b, attn_out);

    // 2. comb: xin = relu([x0|attn] @ comb_W^T + comb_b)  N=1024, K=1024+2048
    gemm_dual<true><<<dim3(OO / 64, BB / 16), dim3(256), 0, stream>>>(
        x, OO, comb_W, OO + HH, 0,
        attn_out, HH, comb_W, OO + HH, OO,
        comb_b, nullptr, xin, OO);

    // 3. LSTM layer 0 -> h1, c1
    lstm_fused<<<dim3(HH / 16, BB / 128), dim3(512), 0, stream>>>(
        xin, OO, Wih0, h0_l0, Whh0, bih0, bhh0, c0_l0, h1, c1);

    // 4. LSTM layer 1 -> h2, c2
    lstm_fused<<<dim3(HH / 16, BB / 128), dim3(512), 0, stream>>>(
        h1, HH, Wih1, h0_l1, Whh1, bih1, bhh1, c0_l1, h2, c2);

    // 5. prediction = h2 @ out_W^T + out_b  N=1024, K=2048
    gemm_dual<false><<<dim3(OO / 64, BB / 16), dim3(256), 0, stream>>>(
        h2, HH, out_W, HH, 0,
        h2, 0, out_W, HH, 0,
        out_b, nullptr, pred, OO);
}

// Round 5
// 531.129 us; speedup vs baseline: 1.7831x; 1.0448x over previous
//
#include <hip/hip_runtime.h>
#include <hip/hip_bf16.h>

typedef short short8 __attribute__((ext_vector_type(8)));
typedef short short4v __attribute__((ext_vector_type(4)));
typedef float floatx4 __attribute__((ext_vector_type(4)));

#define BB 256
#define OO 1024
#define HH 2048
#define SS 12
#define LSTRIDE 40   // 80 B rows: 16B-aligned, 2-way bank aliasing only (free)

__device__ __forceinline__ __hip_bfloat16 f2b(float x) { return __float2bfloat16(x); }
__device__ __forceinline__ float sigf(float x) { return 1.0f / (1.0f + expf(-x)); }

__device__ __forceinline__ short8 cvt8v(float4 lo, float4 hi) {
    union { short8 s; __hip_bfloat16 h[8]; } u;
    u.h[0] = f2b(lo.x); u.h[1] = f2b(lo.y); u.h[2] = f2b(lo.z); u.h[3] = f2b(lo.w);
    u.h[4] = f2b(hi.x); u.h[5] = f2b(hi.y); u.h[6] = f2b(hi.z); u.h[7] = f2b(hi.w);
    return u.s;
}
__device__ __forceinline__ short4v cvt4v(float4 v) {
    union { short4v s; __hip_bfloat16 h[4]; } u;
    u.h[0] = f2b(v.x); u.h[1] = f2b(v.y); u.h[2] = f2b(v.z); u.h[3] = f2b(v.w);
    return u.s;
}
__device__ __forceinline__ unsigned cvt2v(float2 v) {
    union { unsigned s; __hip_bfloat16 h[2]; } u;
    u.h[0] = f2b(v.x); u.h[1] = f2b(v.y);
    return u.s;
}

// ---------------------------------------------------------------------------
// Attention (fp32, float4-vectorized): softmax(concat(x0,h00)@attn_W^T + b)
// over S=12, then attn_out = sum_s w[s]*enc[s]
// ---------------------------------------------------------------------------
__global__ __launch_bounds__(256)
void attn_kernel(const float* __restrict__ x0,
                 const float* __restrict__ h00,
                 const float* __restrict__ enc,
                 const float* __restrict__ attn_W,
                 const float* __restrict__ attn_b,
                 float* __restrict__ attn_out)
{
    const int b = blockIdx.x;
    const int tid = threadIdx.x;
    const int lane = tid & 63;
    const int wave = tid >> 6;

    float part[SS];
#pragma unroll
    for (int s = 0; s < SS; s++) part[s] = 0.f;

    // 3072 floats = 768 float4 chunks; k=0 -> x0 (uniform), k=1,2 -> h00
#pragma unroll
    for (int k = 0; k < 3; k++) {
        const int c = tid + (k << 8);
        float4 v = (k == 0) ? *(const float4*)(x0 + (size_t)b * OO + (c << 2))
                            : *(const float4*)(h00 + (size_t)b * HH + ((c - 256) << 2));
#pragma unroll
        for (int s = 0; s < SS; s++) {
            float4 w4 = *(const float4*)(attn_W + (size_t)s * (OO + HH) + (c << 2));
            part[s] += v.x * w4.x + v.y * w4.y + v.z * w4.z + v.w * w4.w;
        }
    }
#pragma unroll
    for (int s = 0; s < SS; s++) {
#pragma unroll
        for (int off = 32; off > 0; off >>= 1)
            part[s] += __shfl_down(part[s], off);
    }
    __shared__ float red[4][SS];
    __shared__ float wbuf[SS];
    if (lane == 0) {
#pragma unroll
        for (int s = 0; s < SS; s++) red[wave][s] = part[s];
    }
    __syncthreads();
    if (tid == 0) {
        float logits[SS];
        float mx = -1e30f;
        for (int s = 0; s < SS; s++) {
            logits[s] = red[0][s] + red[1][s] + red[2][s] + red[3][s] + attn_b[s];
            mx = fmaxf(mx, logits[s]);
        }
        float sum = 0.f;
        for (int s = 0; s < SS; s++) { logits[s] = expf(logits[s] - mx); sum += logits[s]; }
        float inv = 1.0f / sum;
        for (int s = 0; s < SS; s++) wbuf[s] = logits[s] * inv;
    }
    __syncthreads();

#pragma unroll
    for (int k = 0; k < 2; k++) {
        const int c = tid + (k << 8);       // 512 float4 chunks over 2048
        float4 a = {0.f, 0.f, 0.f, 0.f};
#pragma unroll
        for (int s = 0; s < SS; s++) {
            float4 e = *(const float4*)(enc + ((size_t)(s * BB + b) * HH) + (c << 2));
            float w = wbuf[s];
            a.x += w * e.x; a.y += w * e.y; a.z += w * e.z; a.w += w * e.w;
        }
        *(float4*)(attn_out + (size_t)b * HH + (c << 2)) = a;
    }
}

// ---------------------------------------------------------------------------
// Dual-segment GEMM, depth-3 prefetch: C[256,N] = act(A1@W1^T + A2@W2^T + b)
// fp32 I/O, bf16 MFMA. BM=16, BN=64, BK=32. 256 thr = 4 waves, wave = 16 cols.
// grid (N/64, 16): W-sharing m-blocks co-XCD (ids differ by N/64 = 16 ≡ 0 mod 8).
// ---------------------------------------------------------------------------
template<int K1, int K2, bool RELU>
__global__ __launch_bounds__(256)
void gemm_dual(const float* __restrict__ A1,
               const float* __restrict__ W1, int ldw1, int ofs1,
               const float* __restrict__ A2,
               const float* __restrict__ W2, int ldw2, int ofs2,
               const float* __restrict__ bias1,
               const float* __restrict__ bias2,
               float* __restrict__ Cout, int ldc)
{
    constexpr int n1 = K1 >> 5;
    constexpr int nT = (K1 + K2) >> 5;
    __shared__ __attribute__((aligned(16))) __hip_bfloat16 As[2][16][LSTRIDE];
    __shared__ __attribute__((aligned(16))) __hip_bfloat16 Ws[2][64][LSTRIDE];
    const int tid = threadIdx.x;
    const int lane = tid & 63;
    const int wave = tid >> 6;
    const int quad = lane >> 4, l15 = lane & 15;
    const int m_base = blockIdx.y * 16;
    const int n_base = blockIdx.x * 64;

    // staging: A 16x32 = 512 -> 2 fl/thr; W 64x32 = 2048 -> 8 fl/thr
    const int arow = tid >> 4, acol = (tid & 15) << 1;
    const int wrow = tid >> 2, wcol = (tid & 3) << 3;

    const float* baseA1 = A1 + (size_t)(m_base + arow) * K1 + acol;
    const float* baseA2 = A2 + (size_t)(m_base + arow) * K2 + acol;
    const float* baseW1 = W1 + (size_t)(n_base + wrow) * ldw1 + ofs1 + wcol;
    const float* baseW2 = W2 + (size_t)(n_base + wrow) * ldw2 + ofs2 + wcol;

    float2 pa[4];
    float4 pw0[4], pw1[4];
    auto issue = [&](int tt, int slot) {
        const float *ap, *wp;
        if (tt < n1) { ap = baseA1 + (tt << 5);        wp = baseW1 + (tt << 5); }
        else         { ap = baseA2 + ((tt - n1) << 5); wp = baseW2 + ((tt - n1) << 5); }
        pa[slot]  = *(const float2*)(ap);
        pw0[slot] = *(const float4*)(wp);
        pw1[slot] = *(const float4*)(wp + 4);
    };
#pragma unroll
    for (int p = 0; p < 3; p++) issue(p, p);

    floatx4 acc = (floatx4){0.f, 0.f, 0.f, 0.f};
#pragma unroll 4
    for (int t = 0; t < nT; t++) {
        const int slot = t & 3, buf = t & 1;
        *(unsigned*)(&As[buf][arow][acol]) = cvt2v(pa[slot]);
        *(short8*)(&Ws[buf][wrow][wcol])   = cvt8v(pw0[slot], pw1[slot]);
        __syncthreads();
        if (t + 3 < nT) issue(t + 3, (t + 3) & 3);
        short8 af = *(const short8*)(&As[buf][l15][quad * 8]);
        short8 bf = *(const short8*)(&Ws[buf][wave * 16 + l15][quad * 8]);
        acc = __builtin_amdgcn_mfma_f32_16x16x32_bf16(af, bf, acc, 0, 0, 0);
    }

    // C/D: col=lane&15, row=quad*4+r
    const int col = n_base + wave * 16 + l15;
    float bsum = bias1[col] + (bias2 ? bias2[col] : 0.f);
#pragma unroll
    for (int r = 0; r < 4; r++) {
        const int row = m_base + quad * 4 + r;
        float v = acc[r] + bsum;
        if (RELU) v = fmaxf(v, 0.f);
        Cout[(size_t)row * ldc + col] = v;
    }
}

// ---------------------------------------------------------------------------
// Fused LSTM layer, depth-3 prefetch: gates = A1@Wih^T + A2@Whh^T + bih + bhh
// (W rows i|f|g|o, 2048 each), LSTM cell in epilogue -> h,c fp32.
// 512 thr = 8 waves. BM=64 (4 m-frags), 32 h-cols x 4 gates = 128 W-rows.
// wave = (m-frag = w&3, col-half = w>>2), owns all 4 gates -> 4 MFMA/iter.
// grid (2048/32=64, 256/64=4): W-sharing blocks co-XCD (64 ≡ 0 mod 8).
// ---------------------------------------------------------------------------
template<int K1>
__global__ __launch_bounds__(512)
void lstm_fused(const float* __restrict__ A1,
                const float* __restrict__ Wih,
                const float* __restrict__ A2,   // h_prev [256,2048]
                const float* __restrict__ Whh,  // [8192,2048]
                const float* __restrict__ bih,
                const float* __restrict__ bhh,
                const float* __restrict__ c0,
                float* __restrict__ h_out,
                float* __restrict__ c_out)
{
    constexpr int n1 = K1 >> 5;
    constexpr int nT = n1 + (HH >> 5);
    __shared__ __attribute__((aligned(16))) __hip_bfloat16 As[2][64][LSTRIDE];
    __shared__ __attribute__((aligned(16))) __hip_bfloat16 Ws[2][128][LSTRIDE];
    const int tid = threadIdx.x;
    const int lane = tid & 63;
    const int wave = tid >> 6;           // 0..7
    const int quad = lane >> 4, l15 = lane & 15;
    const int wm = wave & 3;             // m-frag
    const int wc = wave >> 2;            // col-half
    const int m_base = blockIdx.y * 64;
    const int n_base = blockIdx.x * 32;  // h-col base

    // staging: A 64x32 = 2048 -> 4 fl/thr; W 128x32 = 4096 -> 8 fl/thr
    const int arow = tid >> 3, acol = (tid & 7) << 2;
    const int wrow = tid >> 2, wcol = (tid & 3) << 3;
    // Ws row r: gate = r>>5, h-col = n_base + (r&31)
    const int grow = (wrow >> 5) * HH + n_base + (wrow & 31);

    const float* baseA1 = A1 + (size_t)(m_base + arow) * K1 + acol;
    const float* baseA2 = A2 + (size_t)(m_base + arow) * HH + acol;
    const float* baseW1 = Wih + (size_t)grow * K1 + wcol;
    const float* baseW2 = Whh + (size_t)grow * HH + wcol;

    float4 pa[4], pw0[4], pw1[4];
    auto issue = [&](int tt, int slot) {
        const float *ap, *wp;
        if (tt < n1) { ap = baseA1 + (tt << 5);        wp = baseW1 + (tt << 5); }
        else         { ap = baseA2 + ((tt - n1) << 5); wp = baseW2 + ((tt - n1) << 5); }
        pa[slot]  = *(const float4*)(ap);
        pw0[slot] = *(const float4*)(wp);
        pw1[slot] = *(const float4*)(wp + 4);
    };
#pragma unroll
    for (int p = 0; p < 3; p++) issue(p, p);

    floatx4 acc[4];
#pragma unroll
    for (int g = 0; g < 4; g++) acc[g] = (floatx4){0.f, 0.f, 0.f, 0.f};

#pragma unroll 4
    for (int t = 0; t < nT; t++) {
        const int slot = t & 3, buf = t & 1;
        *(short4v*)(&As[buf][arow][acol]) = cvt4v(pa[slot]);
        *(short8*)(&Ws[buf][wrow][wcol])  = cvt8v(pw0[slot], pw1[slot]);
        __syncthreads();
        if (t + 3 < nT) issue(t + 3, (t + 3) & 3);
        short8 af = *(const short8*)(&As[buf][wm * 16 + l15][quad * 8]);
#pragma unroll
        for (int g = 0; g < 4; g++) {
            short8 bf = *(const short8*)(&Ws[buf][g * 32 + wc * 16 + l15][quad * 8]);
            acc[g] = __builtin_amdgcn_mfma_f32_16x16x32_bf16(af, bf, acc[g], 0, 0, 0);
        }
    }

    // epilogue: lane holds i,f,g,o for (row,col); fused LSTM cell, fp32 out.
    const int col = n_base + wc * 16 + l15;
    float bsum[4];
#pragma unroll
    for (int g = 0; g < 4; g++)
        bsum[g] = bih[g * HH + col] + bhh[g * HH + col];

#pragma unroll
    for (int r = 0; r < 4; r++) {
        const int row = m_base + wm * 16 + quad * 4 + r;
        const size_t idx = (size_t)row * HH + col;
        float gi = acc[0][r] + bsum[0];
        float gf = acc[1][r] + bsum[1];
        float gg = acc[2][r] + bsum[2];
        float go = acc[3][r] + bsum[3];
        float c0v = c0[idx];
        float cn = sigf(gf) * c0v + sigf(gi) * tanhf(gg);
        float hn = sigf(go) * tanhf(cn);
        h_out[idx] = hn;
        c_out[idx] = cn;
    }
}

// ---------------------------------------------------------------------------
extern "C" void kernel_launch(void* const* d_in, const int* in_sizes, int n_in,
                              void* d_out, int out_size, void* d_ws, size_t ws_size,
                              hipStream_t stream) {
    const float* x      = (const float*)d_in[0];
    const float* h0     = (const float*)d_in[1];
    const float* c0     = (const float*)d_in[2];
    const float* enc    = (const float*)d_in[3];
    const float* attn_W = (const float*)d_in[4];
    const float* attn_b = (const float*)d_in[5];
    const float* comb_W = (const float*)d_in[6];
    const float* comb_b = (const float*)d_in[7];
    const float* Wih0   = (const float*)d_in[8];
    const float* Whh0   = (const float*)d_in[9];
    const float* bih0   = (const float*)d_in[10];
    const float* bhh0   = (const float*)d_in[11];
    const float* Wih1   = (const float*)d_in[12];
    const float* Whh1   = (const float*)d_in[13];
    const float* bih1   = (const float*)d_in[14];
    const float* bhh1   = (const float*)d_in[15];
    const float* out_W  = (const float*)d_in[16];
    const float* out_b  = (const float*)d_in[17];

    float* pred = (float*)d_out;
    float* h1   = pred + 262144;
    float* h2   = h1 + 524288;
    float* c1   = h2 + 524288;
    float* c2   = c1 + 524288;
    const float* h0_l0 = h0;
    const float* h0_l1 = h0 + 524288;
    const float* c0_l0 = c0;
    const float* c0_l1 = c0 + 524288;

    // Scratch aliased inside d_out (zero d_ws usage):
    //   xin aliases pred (read step 3; pred written step 5)
    //   attn_out aliases c2 (read step 2; c2 written step 4)
    float* xin      = pred;
    float* attn_out = c2;

    // 1. attention
    attn_kernel<<<dim3(BB), dim3(256), 0, stream>>>(x, h0_l0, enc, attn_W, attn_b, attn_out);

    // 2. comb: xin = relu([x0|attn] @ comb_W^T + comb_b)  N=1024, K=1024+2048
    gemm_dual<OO, HH, true><<<dim3(OO / 64, BB / 16), dim3(256), 0, stream>>>(
        x, comb_W, OO + HH, 0,
        attn_out, comb_W, OO + HH, OO,
        comb_b, nullptr, xin, OO);

    // 3. LSTM layer 0 -> h1, c1
    lstm_fused<OO><<<dim3(HH / 32, BB / 64), dim3(512), 0, stream>>>(
        xin, Wih0, h0_l0, Whh0, bih0, bhh0, c0_l0, h1, c1);

    // 4. LSTM layer 1 -> h2, c2
    lstm_fused<HH><<<dim3(HH / 32, BB / 64), dim3(512), 0, stream>>>(
        h1, Wih1, h0_l1, Whh1, bih1, bhh1, c0_l1, h2, c2);

    // 5. prediction = h2 @ out_W^T + out_b  N=1024, K=2048 (K2=0 folds seg 2 away)
    gemm_dual<HH, 0, false><<<dim3(OO / 64, BB / 16), dim3(256), 0, stream>>>(
        h2, out_W, HH, 0,
        h2, out_W, HH, 0,
        out_b, nullptr, pred, OO);
}

// Round 6
// 463.590 us; speedup vs baseline: 2.0429x; 1.1457x over previous
//
#include <hip/hip_runtime.h>
#include <hip/hip_bf16.h>

typedef short short8 __attribute__((ext_vector_type(8)));
typedef short short4v __attribute__((ext_vector_type(4)));
typedef float floatx4 __attribute__((ext_vector_type(4)));

#define BB 256
#define OO 1024
#define HH 2048
#define SS 12
#define LSTRIDE 72   // 64 + 8 pad elems; 144 B rows, 16B-aligned

__device__ __forceinline__ __hip_bfloat16 f2b(float x) { return __float2bfloat16(x); }
__device__ __forceinline__ float sigf(float x) { return 1.0f / (1.0f + expf(-x)); }

__device__ __forceinline__ short8 cvt8v(float4 lo, float4 hi) {
    union { short8 s; __hip_bfloat16 h[8]; } u;
    u.h[0] = f2b(lo.x); u.h[1] = f2b(lo.y); u.h[2] = f2b(lo.z); u.h[3] = f2b(lo.w);
    u.h[4] = f2b(hi.x); u.h[5] = f2b(hi.y); u.h[6] = f2b(hi.z); u.h[7] = f2b(hi.w);
    return u.s;
}
__device__ __forceinline__ short4v cvt4v(float4 v) {
    union { short4v s; __hip_bfloat16 h[4]; } u;
    u.h[0] = f2b(v.x); u.h[1] = f2b(v.y); u.h[2] = f2b(v.z); u.h[3] = f2b(v.w);
    return u.s;
}

// ---------------------------------------------------------------------------
// Attention phase 1: logits + softmax -> wts[256][12]
// ---------------------------------------------------------------------------
__global__ __launch_bounds__(256)
void attn_logits(const float* __restrict__ x0,
                 const float* __restrict__ h00,
                 const float* __restrict__ attn_W,
                 const float* __restrict__ attn_b,
                 float* __restrict__ wts)
{
    const int b = blockIdx.x;
    const int tid = threadIdx.x;
    const int lane = tid & 63;
    const int wave = tid >> 6;

    float part[SS];
#pragma unroll
    for (int s = 0; s < SS; s++) part[s] = 0.f;

#pragma unroll
    for (int k = 0; k < 3; k++) {
        const int c = tid + (k << 8);
        float4 v = (k == 0) ? *(const float4*)(x0 + (size_t)b * OO + (c << 2))
                            : *(const float4*)(h00 + (size_t)b * HH + ((c - 256) << 2));
#pragma unroll
        for (int s = 0; s < SS; s++) {
            float4 w4 = *(const float4*)(attn_W + (size_t)s * (OO + HH) + (c << 2));
            part[s] += v.x * w4.x + v.y * w4.y + v.z * w4.z + v.w * w4.w;
        }
    }
#pragma unroll
    for (int s = 0; s < SS; s++) {
#pragma unroll
        for (int off = 32; off > 0; off >>= 1)
            part[s] += __shfl_down(part[s], off);
    }
    __shared__ float red[4][SS];
    if (lane == 0) {
#pragma unroll
        for (int s = 0; s < SS; s++) red[wave][s] = part[s];
    }
    __syncthreads();
    if (tid == 0) {
        float logits[SS];
        float mx = -1e30f;
        for (int s = 0; s < SS; s++) {
            logits[s] = red[0][s] + red[1][s] + red[2][s] + red[3][s] + attn_b[s];
            mx = fmaxf(mx, logits[s]);
        }
        float sum = 0.f;
        for (int s = 0; s < SS; s++) { logits[s] = expf(logits[s] - mx); sum += logits[s]; }
        float inv = 1.0f / sum;
        for (int s = 0; s < SS; s++) wts[b * SS + s] = logits[s] * inv;
    }
}

// ---------------------------------------------------------------------------
// Attention phase 2: attn_out[b,h] = sum_s wts[b,s]*enc[s,b,h]
// grid = 512: block = (b, h-half of 1024); 256 thr x float4.
// ---------------------------------------------------------------------------
__global__ __launch_bounds__(256)
void attn_apply(const float* __restrict__ enc,
                const float* __restrict__ wts,
                float* __restrict__ attn_out)
{
    const int b = blockIdx.x >> 1;
    const int half = blockIdx.x & 1;
    const int tid = threadIdx.x;
    __shared__ float w[SS];
    if (tid < SS) w[tid] = wts[b * SS + tid];
    __syncthreads();
    const int h = (half << 10) + (tid << 2);
    float4 a = {0.f, 0.f, 0.f, 0.f};
#pragma unroll
    for (int s = 0; s < SS; s++) {
        float4 e = *(const float4*)(enc + ((size_t)(s * BB + b) * HH) + h);
        float ws = w[s];
        a.x += ws * e.x; a.y += ws * e.y; a.z += ws * e.z; a.w += ws * e.w;
    }
    *(float4*)(attn_out + (size_t)b * HH + h) = a;
}

// ---------------------------------------------------------------------------
// Dual-segment GEMM: C[256,N] = act(A1@W1^T + A2@W2^T + b1 + b2)
// fp32 I/O, bf16 MFMA. BM=16, BN=32, BK=64. 256 thr = 4 waves:
// wave = (colfrag cf = w&1, k-half kh = w>>1); k-split reduced via LDS.
// grid (N/32, 16) -> 512 blocks = 2 decoupled blocks/CU.
// ---------------------------------------------------------------------------
template<int K1, int K2, bool RELU>
__global__ __launch_bounds__(256)
void gemm_dual(const float* __restrict__ A1,
               const float* __restrict__ W1, int ldw1, int ofs1,
               const float* __restrict__ A2,
               const float* __restrict__ W2, int ldw2, int ofs2,
               const float* __restrict__ bias1,
               const float* __restrict__ bias2,
               float* __restrict__ Cout, int ldc)
{
    constexpr int n1 = K1 >> 6;
    constexpr int nT = (K1 + K2) >> 6;
    __shared__ __attribute__((aligned(16))) __hip_bfloat16 As[2][16][LSTRIDE];
    __shared__ __attribute__((aligned(16))) __hip_bfloat16 Ws[2][32][LSTRIDE];
    __shared__ float red[2][16][17];
    const int tid = threadIdx.x;
    const int lane = tid & 63;
    const int wave = tid >> 6;
    const int quad = lane >> 4, l15 = lane & 15;
    const int cf = wave & 1;   // col frag (16 cols each)
    const int kh = wave >> 1;  // k-half (32 each within BK=64)
    const int m_base = blockIdx.y * 16;
    const int n_base = blockIdx.x * 32;

    // staging: A 16x64 = 1024 el -> 4/thr (1 f4); W 32x64 = 2048 -> 8/thr (2 f4)
    const int arow = tid >> 4, acol = (tid & 15) << 2;
    const int wrow = tid >> 3, wcol = (tid & 7) << 3;

    const float* baseA1 = A1 + (size_t)(m_base + arow) * K1 + acol;
    const float* baseA2 = A2 + (size_t)(m_base + arow) * K2 + acol;
    const float* baseW1 = W1 + (size_t)(n_base + wrow) * ldw1 + ofs1 + wcol;
    const float* baseW2 = W2 + (size_t)(n_base + wrow) * ldw2 + ofs2 + wcol;

    float4 pa, pw0, pw1;
    auto issue = [&](int tt) {
        const float *ap, *wp;
        if (tt < n1) { ap = baseA1 + (tt << 6);        wp = baseW1 + (tt << 6); }
        else         { ap = baseA2 + ((tt - n1) << 6); wp = baseW2 + ((tt - n1) << 6); }
        pa  = *(const float4*)(ap);
        pw0 = *(const float4*)(wp);
        pw1 = *(const float4*)(wp + 4);
    };
    issue(0);

    floatx4 acc = (floatx4){0.f, 0.f, 0.f, 0.f};
    for (int t = 0; t < nT; t++) {
        const int buf = t & 1;
        *(short4v*)(&As[buf][arow][acol]) = cvt4v(pa);
        *(short8*)(&Ws[buf][wrow][wcol])  = cvt8v(pw0, pw1);
        __syncthreads();
        if (t + 1 < nT) issue(t + 1);
        short8 af = *(const short8*)(&As[buf][l15][kh * 32 + quad * 8]);
        short8 bf = *(const short8*)(&Ws[buf][cf * 16 + l15][kh * 32 + quad * 8]);
        acc = __builtin_amdgcn_mfma_f32_16x16x32_bf16(af, bf, acc, 0, 0, 0);
    }

    // k-split reduction: kh=1 waves stash, kh=0 waves combine + epilogue.
    if (kh == 1) {
#pragma unroll
        for (int r = 0; r < 4; r++) red[cf][l15][quad * 4 + r] = acc[r];
    }
    __syncthreads();
    if (kh == 0) {
        const int col = n_base + cf * 16 + l15;
        float bsum = bias1[col] + (bias2 ? bias2[col] : 0.f);
#pragma unroll
        for (int r = 0; r < 4; r++) {
            const int row = m_base + quad * 4 + r;
            float v = acc[r] + red[cf][l15][quad * 4 + r] + bsum;
            if (RELU) v = fmaxf(v, 0.f);
            Cout[(size_t)row * ldc + col] = v;
        }
    }
}

// ---------------------------------------------------------------------------
// Fused LSTM layer: gates = A1@Wih^T + A2@Whh^T + bih + bhh (W rows i|f|g|o),
// LSTM cell in epilogue. 256 thr = 4 waves; BM=64 (wave = 16-row m-frag),
// 16 h-cols x 4 gates = 64 W-rows; BK=64.
// grid (2048/16=128, 4) = 512 blocks = 2 decoupled blocks/CU.
// W-sharing m-blocks co-XCD (ids differ by 128 = 0 mod 8).
// ---------------------------------------------------------------------------
template<int K1>
__global__ __launch_bounds__(256)
void lstm_fused(const float* __restrict__ A1,
                const float* __restrict__ Wih,
                const float* __restrict__ A2,   // h_prev [256,2048]
                const float* __restrict__ Whh,  // [8192,2048]
                const float* __restrict__ bih,
                const float* __restrict__ bhh,
                const float* __restrict__ c0,
                float* __restrict__ h_out,
                float* __restrict__ c_out)
{
    constexpr int n1 = K1 >> 6;
    constexpr int nT = n1 + (HH >> 6);
    __shared__ __attribute__((aligned(16))) __hip_bfloat16 As[2][64][LSTRIDE];
    __shared__ __attribute__((aligned(16))) __hip_bfloat16 Ws[2][64][LSTRIDE];
    const int tid = threadIdx.x;
    const int lane = tid & 63;
    const int wave = tid >> 6;           // m-frag
    const int quad = lane >> 4, l15 = lane & 15;
    const int m_base = blockIdx.y * 64;
    const int n_base = blockIdx.x * 16;  // h-col base

    // staging: A 64x64 = 4096 el -> 16/thr (4 f4); W 64x64 same.
    const int arow = tid >> 2, acol = (tid & 3) << 4;
    // Ws row r: gate = r>>4, h-col = n_base + (r&15)
    const int grow = (arow >> 4) * HH + n_base + (arow & 15);

    const float* baseA1 = A1 + (size_t)(m_base + arow) * K1 + acol;
    const float* baseA2 = A2 + (size_t)(m_base + arow) * HH + acol;
    const float* baseW1 = Wih + (size_t)grow * K1 + acol;
    const float* baseW2 = Whh + (size_t)grow * HH + acol;

    float4 pa[4], pw[4];
    auto issue = [&](int tt) {
        const float *ap, *wp;
        if (tt < n1) { ap = baseA1 + (tt << 6);        wp = baseW1 + (tt << 6); }
        else         { ap = baseA2 + ((tt - n1) << 6); wp = baseW2 + ((tt - n1) << 6); }
#pragma unroll
        for (int j = 0; j < 4; j++) {
            pa[j] = *(const float4*)(ap + (j << 2));
            pw[j] = *(const float4*)(wp + (j << 2));
        }
    };
    issue(0);

    floatx4 acc[4];
#pragma unroll
    for (int g = 0; g < 4; g++) acc[g] = (floatx4){0.f, 0.f, 0.f, 0.f};

    for (int t = 0; t < nT; t++) {
        const int buf = t & 1;
        *(short8*)(&As[buf][arow][acol])     = cvt8v(pa[0], pa[1]);
        *(short8*)(&As[buf][arow][acol + 8]) = cvt8v(pa[2], pa[3]);
        *(short8*)(&Ws[buf][arow][acol])     = cvt8v(pw[0], pw[1]);
        *(short8*)(&Ws[buf][arow][acol + 8]) = cvt8v(pw[2], pw[3]);
        __syncthreads();
        if (t + 1 < nT) issue(t + 1);
#pragma unroll
        for (int k = 0; k < 2; k++) {
            short8 af = *(const short8*)(&As[buf][wave * 16 + l15][k * 32 + quad * 8]);
#pragma unroll
            for (int g = 0; g < 4; g++) {
                short8 bf = *(const short8*)(&Ws[buf][g * 16 + l15][k * 32 + quad * 8]);
                acc[g] = __builtin_amdgcn_mfma_f32_16x16x32_bf16(af, bf, acc[g], 0, 0, 0);
            }
        }
    }

    // epilogue: lane holds i,f,g,o for (row,col); fused LSTM cell, fp32 out.
    const int col = n_base + l15;
    float bsum[4];
#pragma unroll
    for (int g = 0; g < 4; g++)
        bsum[g] = bih[g * HH + col] + bhh[g * HH + col];

#pragma unroll
    for (int r = 0; r < 4; r++) {
        const int row = m_base + wave * 16 + quad * 4 + r;
        const size_t idx = (size_t)row * HH + col;
        float gi = acc[0][r] + bsum[0];
        float gf = acc[1][r] + bsum[1];
        float gg = acc[2][r] + bsum[2];
        float go = acc[3][r] + bsum[3];
        float c0v = c0[idx];
        float cn = sigf(gf) * c0v + sigf(gi) * tanhf(gg);
        float hn = sigf(go) * tanhf(cn);
        h_out[idx] = hn;
        c_out[idx] = cn;
    }
}

// ---------------------------------------------------------------------------
extern "C" void kernel_launch(void* const* d_in, const int* in_sizes, int n_in,
                              void* d_out, int out_size, void* d_ws, size_t ws_size,
                              hipStream_t stream) {
    const float* x      = (const float*)d_in[0];
    const float* h0     = (const float*)d_in[1];
    const float* c0     = (const float*)d_in[2];
    const float* enc    = (const float*)d_in[3];
    const float* attn_W = (const float*)d_in[4];
    const float* attn_b = (const float*)d_in[5];
    const float* comb_W = (const float*)d_in[6];
    const float* comb_b = (const float*)d_in[7];
    const float* Wih0   = (const float*)d_in[8];
    const float* Whh0   = (const float*)d_in[9];
    const float* bih0   = (const float*)d_in[10];
    const float* bhh0   = (const float*)d_in[11];
    const float* Wih1   = (const float*)d_in[12];
    const float* Whh1   = (const float*)d_in[13];
    const float* bih1   = (const float*)d_in[14];
    const float* bhh1   = (const float*)d_in[15];
    const float* out_W  = (const float*)d_in[16];
    const float* out_b  = (const float*)d_in[17];

    float* pred = (float*)d_out;
    float* h1   = pred + 262144;
    float* h2   = h1 + 524288;
    float* c1   = h2 + 524288;
    float* c2   = c1 + 524288;
    const float* h0_l0 = h0;
    const float* h0_l1 = h0 + 524288;
    const float* c0_l0 = c0;
    const float* c0_l1 = c0 + 524288;

    // Scratch aliased inside d_out (zero d_ws usage):
    //   xin aliases pred       (read step 4; pred written step 6)
    //   attn_out aliases c2    (read step 3; c2 written step 5)
    //   wts aliases c1 start   (read step 2; c1 written step 4)
    float* xin      = pred;
    float* attn_out = c2;
    float* wts      = c1;

    // 1. attention logits + softmax
    attn_logits<<<dim3(BB), dim3(256), 0, stream>>>(x, h0_l0, attn_W, attn_b, wts);

    // 2. attention apply
    attn_apply<<<dim3(BB * 2), dim3(256), 0, stream>>>(enc, wts, attn_out);

    // 3. comb: xin = relu([x0|attn] @ comb_W^T + comb_b)  N=1024, K=1024+2048
    gemm_dual<OO, HH, true><<<dim3(OO / 32, BB / 16), dim3(256), 0, stream>>>(
        x, comb_W, OO + HH, 0,
        attn_out, comb_W, OO + HH, OO,
        comb_b, nullptr, xin, OO);

    // 4. LSTM layer 0 -> h1, c1
    lstm_fused<OO><<<dim3(HH / 16, BB / 64), dim3(256), 0, stream>>>(
        xin, Wih0, h0_l0, Whh0, bih0, bhh0, c0_l0, h1, c1);

    // 5. LSTM layer 1 -> h2, c2
    lstm_fused<HH><<<dim3(HH / 16, BB / 64), dim3(256), 0, stream>>>(
        h1, Wih1, h0_l1, Whh1, bih1, bhh1, c0_l1, h2, c2);

    // 6. prediction = h2 @ out_W^T + out_b  N=1024, K=2048
    gemm_dual<HH, 0, false><<<dim3(OO / 32, BB / 16), dim3(256), 0, stream>>>(
        h2, out_W, HH, 0,
        h2, out_W, HH, 0,
        out_b, nullptr, pred, OO);
}